// Round 2
// baseline (182.552 us; speedup 1.0000x reference)
//
#include <hip/hip_runtime.h>

typedef float  f32x4  __attribute__((ext_vector_type(4)));
typedef short  bf16x8 __attribute__((ext_vector_type(8)));

#define HWI    16384          // 128*128
#define IMG    (96*16384)     // per-batch elements
#define NPIX   50331648       // 32*96*128*128

// ws layout (float offsets)
#define WS_G   0              // 9216 floats: G = convq^T @ convk
#define WS_SP  16384          // 512 blocks * 8 partial floats = 4096
#define WS_A   20480          // 32 b * 8 floats: finished attn components
#define WS_CTR 20736          // 1040 ints: gcnt / bcnt[32] / aflag[32] (padded)

#define SPIN_MAX (1 << 22)    // bounded spin: worst case ~0.3 s, never a hang

__device__ __forceinline__ unsigned short f2bf(float f){
    unsigned u = __builtin_bit_cast(unsigned, f);
    u += 0x7fffu + ((u >> 16) & 1u);          // round-to-nearest-even
    return (unsigned short)(u >> 16);
}

// rebuild one attn-matrix component from the 8 ks-block partials
__device__ __forceinline__ float attn_comp(const float* __restrict__ sp, int b, int w2,
                                           int comp, float o1, float o2, float o3){
    const int s0 = (comp == 0) ? 0 : (comp == 1) ? 2 : (comp == 2) ? 6 : 4;
    const float* base = sp + (size_t)((b*2 + w2) * 8) * 8;
    float s = 0.f;
    #pragma unroll
    for (int k2 = 0; k2 < 8; ++k2) s += base[k2*8 + s0] + base[k2*8 + s0 + 1];
    s += o2;
    s = (s >= 0.f ? s : 1e-4f * s) + o3;
    if (comp == 0 || comp == 3) s += o1;
    return s;
}

// =====================================================================
// Single fused kernel, PLAIN launch (no cooperative / no grid.sync):
//  - blocks 0..23 compute G first (done in ~2us, consumed ~30us later)
//  - phase 1: Gram MFMA loop (identical to the verified kM)
//  - epilogue: bounded acquire-spin on gcnt, dot with G -> partials
//  - per-b last finisher (atomic fetch_add) computes A + logdet, releases
//  - phase 2: bounded acquire-spin on aflag[b], then each block writes the
//    exact x-region it streamed in phase 1 (same CU/XCD; rows reversed so
//    the freshest lines hit L2), nontemporal stores.
// 512 blocks x 384 threads = exactly 2 blocks/CU -> all co-resident; all
// spins are bounded so a scheduling anomaly degrades to a measurable run.
// =====================================================================
__launch_bounds__(384, 3)
__global__ void kFused(const float* __restrict__ x, const float* __restrict__ cq,
                       const float* __restrict__ ck, float* __restrict__ ws,
                       const float* __restrict__ o1p, const float* __restrict__ o2p,
                       const float* __restrict__ o3p, float* __restrict__ out)
{
    float* G    = ws + WS_G;
    float* sp   = ws + WS_SP;
    float* Aws  = ws + WS_A;
    int*   ci   = (int*)(ws + WS_CTR);
    int*   gcnt = ci;                                  // [0]

    const int blk = blockIdx.x;
    const int b = blk >> 4, wp = (blk >> 3) & 1, ks = blk & 7;
    const int tid = threadIdx.x;
    const int wave = tid >> 6, lane = tid & 63;
    const int q  = wave >> 1;                  // 0 tt, 1 tb, 2 bb
    const int h  = wave & 1;                   // row-half of quadrant
    const int qr = (q == 2) ? 1 : 0;
    const int qc = (q == 0) ? 0 : 1;

    int* bcnt_b  = ci + 16  + b * 16;
    int* aflag_b = ci + 528 + b * 16;

    __shared__ unsigned short Zs[2][192][40];  // double buffer, 32 valid k + pad
    __shared__ float As8[8];
    __shared__ int   isLast;

    // ---- G by blocks 0..23 (24*384 = 9216 entries), overlapped with phase 1
    if (blk < 24){
        const int idx = blk * 384 + tid;
        const int c = idx / 96, cp = idx - c * 96;
        float s = 0.f;
        #pragma unroll 8
        for (int o = 0; o < 96; ++o) s += cq[o*96 + c] * ck[o*96 + cp];
        G[idx] = s;
        __syncthreads();
        if (tid == 0){
            __threadfence();                   // publish G (writeback to device scope)
            __hip_atomic_fetch_add(gcnt, 1, __ATOMIC_RELEASE, __HIP_MEMORY_SCOPE_AGENT);
        }
    }

    // ---------------- phase 1: Gram via MFMA (identical to verified kM) ---------
    f32x4 acc[3][6];
    #pragma unroll
    for (int a = 0; a < 3; ++a)
      #pragma unroll
      for (int b2 = 0; b2 < 6; ++b2)
        acc[a][b2] = (f32x4){0.f, 0.f, 0.f, 0.f};

    const int l16 = tid & 15, rr = tid >> 4;   // rr in [0,24)
    const float* xb = x + (size_t)b * IMG + wp * 64 + l16 * 4;
    const int frow = lane & 15, fko = (lane >> 4) << 3;

    f32x4 v[8];
    {   // prologue: load step 0
        const int i0 = ks * 8;
        #pragma unroll
        for (int p = 0; p < 8; ++p){
            const int row = rr + p * 24;
            const int cch = (row < 96) ? row : row - 96;
            const int hh  = (row < 96) ? i0  : i0 + 64;
            v[p] = *(const f32x4*)(xb + (size_t)cch * HWI + hh * 128);
        }
    }

    for (int step = 0; step < 8; ++step){
        const int cur = step & 1;
        #pragma unroll
        for (int p = 0; p < 8; ++p){
            const int row = rr + p * 24;
            unsigned pk = (wp == 0)
                ? ((unsigned)f2bf(v[p][0]) | ((unsigned)f2bf(v[p][2]) << 16))
                : ((unsigned)f2bf(v[p][1]) | ((unsigned)f2bf(v[p][3]) << 16));
            *(unsigned*)(&Zs[cur][row][l16 * 2]) = pk;
        }
        __syncthreads();
        if (step < 7){
            const int i = ks * 8 + step + 1;
            #pragma unroll
            for (int p = 0; p < 8; ++p){
                const int row = rr + p * 24;
                const int cch = (row < 96) ? row : row - 96;
                const int hh  = (row < 96) ? i   : i + 64;
                v[p] = *(const f32x4*)(xb + (size_t)cch * HWI + hh * 128);
            }
        }
        bf16x8 af[3], bfv[6];
        #pragma unroll
        for (int t3 = 0; t3 < 3; ++t3)
            af[t3] = *(const bf16x8*)(&Zs[cur][qr*96 + (h*3 + t3)*16 + frow][fko]);
        #pragma unroll
        for (int t6 = 0; t6 < 6; ++t6)
            bfv[t6] = *(const bf16x8*)(&Zs[cur][qc*96 + t6*16 + frow][fko]);
        #pragma unroll
        for (int tr = 0; tr < 3; ++tr)
          #pragma unroll
          for (int tc = 0; tc < 6; ++tc)
            acc[tr][tc] = __builtin_amdgcn_mfma_f32_16x16x32_bf16(
                              af[tr], bfv[tc], acc[tr][tc], 0, 0, 0);
    }

    // ---- wait for G (done ~28us ago in the normal case; bounded spin) ----------
    if (tid == 0){
        int it = 0;
        while (__hip_atomic_load(gcnt, __ATOMIC_ACQUIRE, __HIP_MEMORY_SCOPE_AGENT) < 24
               && it < SPIN_MAX){ __builtin_amdgcn_s_sleep(1); ++it; }
        __threadfence();                       // acquire: invalidate stale L1/L2 lines
    }
    __syncthreads();

    // ---------------- epilogue: fused dot with G (and G^T for tb) ----------------
    {
        const int r0 = (lane >> 4) * 4, c0 = lane & 15;
        float p0 = 0.f, p1 = 0.f;
        #pragma unroll
        for (int tr = 0; tr < 3; ++tr){
          #pragma unroll
          for (int tc = 0; tc < 6; ++tc){
            #pragma unroll
            for (int e = 0; e < 4; ++e){
              const int R = (h*3 + tr)*16 + r0 + e;
              const int C = tc*16 + c0;
              const float m = acc[tr][tc][e];
              p0 += G[R*96 + C] * m;
              if (q == 1) p1 += G[C*96 + R] * m;
            }
          }
        }
        #pragma unroll
        for (int off = 32; off > 0; off >>= 1){
            p0 += __shfl_down(p0, off, 64);
            if (q == 1) p1 += __shfl_down(p1, off, 64);
        }
        if (lane == 0){
            float* s = sp + (size_t)blk * 8;
            s[wave] = p0;                      // slots 0..5
            if (q == 1) s[6 + h] = p1;         // slots 6..7 (bt)
        }
    }
    __syncthreads();

    // ---- per-b last finisher computes A + logdet, then releases aflag[b] --------
    const float o1 = o1p[0], o2 = o2p[0], o3 = o3p[0];
    if (tid == 0){
        __threadfence();                       // publish this block's sp slots
        int prev = __hip_atomic_fetch_add(bcnt_b, 1, __ATOMIC_ACQ_REL,
                                          __HIP_MEMORY_SCOPE_AGENT);
        isLast = (prev == 15);
        if (prev == 15) __threadfence();       // acquire: see all 16 blocks' sp
    }
    __syncthreads();
    if (isLast){
        if (tid < 8){
            const int w2 = tid >> 2, comp = tid & 3;
            As8[tid] = attn_comp(sp, b, w2, comp, o1, o2, o3);
        }
        __syncthreads();
        if (tid == 0){
            const float d0 = As8[0]*As8[3] - As8[1]*As8[2];
            const float d1 = As8[4]*As8[7] - As8[5]*As8[6];
            out[NPIX + b] = (logf(fabsf(d0)) + logf(fabsf(d1))) * 196608.0f;
            #pragma unroll
            for (int i2 = 0; i2 < 8; ++i2) Aws[b*8 + i2] = As8[i2];
            __threadfence();                   // publish A before the flag
            __hip_atomic_store(aflag_b, 1, __ATOMIC_RELEASE, __HIP_MEMORY_SCOPE_AGENT);
        }
    }

    // ---- wait for A (siblings finish within ~us; bounded spin) ------------------
    if (tid == 0){
        int it = 0;
        while (__hip_atomic_load(aflag_b, __ATOMIC_ACQUIRE, __HIP_MEMORY_SCOPE_AGENT) == 0
               && it < SPIN_MAX){ __builtin_amdgcn_s_sleep(1); ++it; }
        __threadfence();
    }
    __syncthreads();

    // atomic loads for the 4 A floats: coherent regardless of stale clean L2 lines
    const float a00 = __hip_atomic_load(Aws + b*8 + wp*4 + 0, __ATOMIC_RELAXED, __HIP_MEMORY_SCOPE_AGENT);
    const float a01 = __hip_atomic_load(Aws + b*8 + wp*4 + 1, __ATOMIC_RELAXED, __HIP_MEMORY_SCOPE_AGENT);
    const float a10 = __hip_atomic_load(Aws + b*8 + wp*4 + 2, __ATOMIC_RELAXED, __HIP_MEMORY_SCOPE_AGENT);
    const float a11 = __hip_atomic_load(Aws + b*8 + wp*4 + 3, __ATOMIC_RELAXED, __HIP_MEMORY_SCOPE_AGENT);

    // ---------------- phase 2: output over this block's OWN phase-1 region -------
    // region: batch b, col-half wp, spatial rows [ks*8, ks*8+8) (+64 bottom),
    // all 96 channels. Rows walked in reverse so phase-1's freshest lines L2-hit.
    const float* xb2 = x   + (size_t)b * IMG + wp * 64;
    float*       ob2 = out + (size_t)b * IMG + wp * 64;

    #pragma unroll 1
    for (int g2 = 0; g2 < 8; ++g2){
        f32x4 tv[4], bv[4];
        int offs[4];
        #pragma unroll
        for (int u = 0; u < 4; ++u){           // batch loads: 8 x 16B in flight
            const int pi  = (g2*4 + u)*384 + tid;
            const int ch  = pi >> 7;           // 0..95
            const int rem = pi & 127;
            const int row = 7 - (rem >> 4);    // reverse: freshest rows first
            const int cv  = rem & 15;
            offs[u] = ch * HWI + (ks*8 + row) * 128 + cv * 4;
            tv[u] = *(const f32x4*)(xb2 + offs[u]);
            bv[u] = *(const f32x4*)(xb2 + offs[u] + 8192);
        }
        #pragma unroll
        for (int u = 0; u < 4; ++u){
            f32x4 ot, ob;
            #pragma unroll
            for (int e = 0; e < 4; ++e){
                const bool mix = ((wp + e) & 1) != 0;
                ot[e] = mix ? (a00 * tv[u][e] + a01 * bv[u][e]) : tv[u][e];
                ob[e] = mix ? (a10 * tv[u][e] + a11 * bv[u][e]) : bv[u][e];
            }
            __builtin_nontemporal_store(ot, (f32x4*)(ob2 + offs[u]));
            __builtin_nontemporal_store(ob, (f32x4*)(ob2 + offs[u] + 8192));
        }
    }
}

extern "C" void kernel_launch(void* const* d_in, const int* in_sizes, int n_in,
                              void* d_out, int out_size, void* d_ws, size_t ws_size,
                              hipStream_t stream){
    const float* x  = (const float*)d_in[0];
    const float* cq = (const float*)d_in[1];
    const float* ck = (const float*)d_in[2];
    const float* o1 = (const float*)d_in[3];
    const float* o2 = (const float*)d_in[4];
    const float* o3 = (const float*)d_in[5];
    float* out = (float*)d_out;
    float* ws  = (float*)d_ws;

    // zero the sync counters (graph-capturable memset node, runs every replay)
    hipMemsetAsync((void*)(ws + WS_CTR), 0, 1040 * sizeof(int), stream);
    kFused<<<512, 384, 0, stream>>>(x, cq, ck, ws, o1, o2, o3, out);
}